// Round 6
// baseline (288.569 us; speedup 1.0000x reference)
//
#include <hip/hip_runtime.h>
#include <cstdint>

#define NROWS 131072
#define HD    128      // H == IN == 128
#define NDIM  512      // 4*H
#define OUTQ  16777216 // NROWS*HD

using bf16x8 = __attribute__((ext_vector_type(8))) short;
using f32x4  = __attribute__((ext_vector_type(4))) float;

__device__ __forceinline__ uint32_t bf16rne(float f) {
  uint32_t u = __builtin_bit_cast(uint32_t, f);
  return (u + 0x7fffu + ((u >> 16) & 1u)) >> 16;
}

__device__ __forceinline__ float tanhf_fast(float v) {
  float a = __builtin_fabsf(v);
  float e = __expf(-2.0f * a);
  float t = (1.0f - e) * __builtin_amdgcn_rcpf(1.0f + e);
  return v < 0.0f ? -t : t;
}

__device__ __forceinline__ f32x4 ldv(const float* p) {
  return *reinterpret_cast<const f32x4*>(p);
}

// Async global->LDS DMA, 16B per lane. LDS dest = uniform base + lane*16.
#define ASYNC16(g, l)                                                        \
  __builtin_amdgcn_global_load_lds(                                          \
      (const __attribute__((address_space(1))) void*)(g),                    \
      (__attribute__((address_space(3))) void*)(l), 16, 0, 0)

// Pack Wf[k][n] = W[k][n] + (k>=128 ? r[k-128][n] : 0) as bf16 fragments.
// Frag (g*8 + t)*8 + s (1 KB each): element j of lane l =
//   Wf[s*32 + (l>>4)*8 + j][gate g, col t*16 + (l&15)].
__global__ __launch_bounds__(256) void pack_weights(
    const float* __restrict__ W, const float* __restrict__ r,
    uint16_t* __restrict__ Bp) {
  int idx = blockIdx.x * 256 + threadIdx.x;   // 16384 frags total
  int l  = idx & 63;
  int ts = idx >> 6;
  int s  = ts & 7;
  int t  = ts >> 3;
  int ncol  = t * 16 + (l & 15);
  int kbase = s * 32 + ((l >> 4) << 3);
  uint32_t w[4];
#pragma unroll
  for (int jj = 0; jj < 4; ++jj) {
    int k0 = kbase + 2 * jj;
    float v0 = W[k0 * NDIM + ncol];
    float v1 = W[(k0 + 1) * NDIM + ncol];
    if (k0 >= 128)     v0 += r[(k0 - 128) * NDIM + ncol];
    if (k0 + 1 >= 128) v1 += r[(k0 + 1 - 128) * NDIM + ncol];
    w[jj] = bf16rne(v0) | (bf16rne(v1) << 16);
  }
  reinterpret_cast<uint4*>(Bp)[idx] = make_uint4(w[0], w[1], w[2], w[3]);
}

__global__ __launch_bounds__(256, 2) void slstm_fused(
    const float* __restrict__ x,  const float* __restrict__ h,
    const float* __restrict__ cs, const float* __restrict__ ns,
    const float* __restrict__ ms, const float* __restrict__ bias,
    const uint16_t* __restrict__ Bp, float* __restrict__ out) {
  // 32 KB LDS, time-shared: (1) x|h staging, (2) weight tile buffer,
  // (3) output transpose buffer for coalesced 1KB stores.
  __shared__ __align__(16) char smem[32768];
  const int tid  = threadIdx.x;
  const int wave = tid >> 6;
  const int lane = tid & 63;
  const int row0 = blockIdx.x * 64;
  const int l15  = lane & 15;
  const int lg   = lane >> 4;

  const int    myrow = row0 + wave * 16 + l15;
  const size_t rbase = (size_t)myrow * HD;
  const int    jb    = lg * 4;

  // ---- stage x (cols 0..127) then h (cols 128..255) as bf16, XOR-swizzled ----
#pragma unroll
  for (int i = 0; i < 8; ++i) {
    int e   = (i * 256 + tid) * 4;
    int rw  = e >> 7;
    int col = e & 127;
    float4 v = *reinterpret_cast<const float4*>(x + (size_t)(row0 + rw) * HD + col);
    uint32_t lo = bf16rne(v.x) | (bf16rne(v.y) << 16);
    uint32_t hi = bf16rne(v.z) | (bf16rne(v.w) << 16);
    int off = (rw * 512 + col * 2) ^ ((rw & 7) << 4);
    *reinterpret_cast<uint2*>(smem + off) = make_uint2(lo, hi);
  }
#pragma unroll
  for (int i = 0; i < 8; ++i) {
    int e   = (i * 256 + tid) * 4;
    int rw  = e >> 7;
    int col = e & 127;
    float4 v = *reinterpret_cast<const float4*>(h + (size_t)(row0 + rw) * HD + col);
    uint32_t lo = bf16rne(v.x) | (bf16rne(v.y) << 16);
    uint32_t hi = bf16rne(v.z) | (bf16rne(v.w) << 16);
    int off = (rw * 512 + 256 + col * 2) ^ ((rw & 7) << 4);
    *reinterpret_cast<uint2*>(smem + off) = make_uint2(lo, hi);
  }
  __syncthreads();

  // ---- x|h fragments (MFMA B-operand) ----
  bf16x8 a[8];
  {
    int rw   = wave * 16 + l15;
    int base = rw * 512 + (lg << 4);
    int swz  = (rw & 7) << 4;
#pragma unroll
    for (int s = 0; s < 8; ++s)
      a[s] = *reinterpret_cast<const bf16x8*>(smem + ((base + s * 64) ^ swz));
  }
  __syncthreads();   // region handoff: staging area becomes weight buffer

  const char* wBytes = (const char*)Bp;
  // DMA tile 0: wave w stages gate w, k-steps 0..7
  {
    const char* gsrc = wBytes + (((size_t)(wave * 8 + 0) * 8) << 10) + (lane << 4);
    char* ldst = smem + (wave << 13);
#pragma unroll
    for (int k = 0; k < 8; ++k)
      ASYNC16(gsrc + (k << 10), ldst + (k << 10));
  }

  // Per-tile outputs held in registers (static indices via full unroll).
  f32x4 oH[8], oC[8], oN[8], oM[8];

  // ---- 8 column tiles, fully unrolled ----
#pragma unroll
  for (int t = 0; t < 8; ++t) {
    __syncthreads();   // vm drain -> tile t weights visible to all waves

    const size_t pc = rbase + jb + 16 * t;
    const f32x4 cv = ldv(cs + pc);
    const f32x4 nv = ldv(ns + pc);
    const f32x4 mv = ldv(ms + pc);
    const int j0 = jb + 16 * t;
    const f32x4 bI = ldv(bias + j0);
    const f32x4 bF = ldv(bias + 128 + j0);
    const f32x4 bZ = ldv(bias + 256 + j0);
    const f32x4 bO = ldv(bias + 384 + j0);

    f32x4 accI = {0.f, 0.f, 0.f, 0.f};
    f32x4 accF = {0.f, 0.f, 0.f, 0.f};
    f32x4 accZ = {0.f, 0.f, 0.f, 0.f};
    f32x4 accO = {0.f, 0.f, 0.f, 0.f};
#pragma unroll
    for (int s = 0; s < 8; ++s) {
      const int lo = lane << 4;
      bf16x8 wI = *reinterpret_cast<const bf16x8*>(smem + ((0 * 8 + s) << 10) + lo);
      bf16x8 wF = *reinterpret_cast<const bf16x8*>(smem + ((1 * 8 + s) << 10) + lo);
      bf16x8 wZ = *reinterpret_cast<const bf16x8*>(smem + ((2 * 8 + s) << 10) + lo);
      bf16x8 wO = *reinterpret_cast<const bf16x8*>(smem + ((3 * 8 + s) << 10) + lo);
      accI = __builtin_amdgcn_mfma_f32_16x16x32_bf16(wI, a[s], accI, 0, 0, 0);
      accF = __builtin_amdgcn_mfma_f32_16x16x32_bf16(wF, a[s], accF, 0, 0, 0);
      accZ = __builtin_amdgcn_mfma_f32_16x16x32_bf16(wZ, a[s], accZ, 0, 0, 0);
      accO = __builtin_amdgcn_mfma_f32_16x16x32_bf16(wO, a[s], accO, 0, 0, 0);
    }
    __syncthreads();   // all waves done reading tile t weights

    if (t < 7) {       // DMA tile t+1; latency hides under epilogue
      const char* gsrc = wBytes + (((size_t)(wave * 8 + (t + 1)) * 8) << 10) + (lane << 4);
      char* ldst = smem + (wave << 13);
#pragma unroll
      for (int k = 0; k < 8; ++k)
        ASYNC16(gsrc + (k << 10), ldst + (k << 10));
    }

    f32x4 hn, cn, nn, mn;
#pragma unroll
    for (int rr = 0; rr < 4; ++rr) {
      float i_raw = accI[rr] + bI[rr];
      float f_raw = accF[rr] + bF[rr];
      float z_raw = accZ[rr] + bZ[rr];
      float o_raw = accO[rr] + bO[rr];
      float ef  = __expf(-f_raw);
      float den = 1.0f + ef;
      float fg  = __builtin_amdgcn_rcpf(den);   // sigmoid(f_raw)
      float lgf = -__logf(den);                 // log sigmoid(f_raw)
      float mnv = fmaxf(lgf + mv[rr], i_raw);   // m_new
      float ip  = __expf(i_raw - mnv);          // i'
      float zt  = tanhf_fast(z_raw);
      float og  = __builtin_amdgcn_rcpf(1.0f + __expf(-o_raw));
      float cnv = fg * cv[rr] + ip * zt;        // c_new (f' == f per source)
      float nnv = fg * nv[rr] + ip;             // n_new
      hn[rr] = og * tanhf_fast(cnv * __builtin_amdgcn_rcpf(nnv));
      cn[rr] = cnv;
      nn[rr] = nnv;
      mn[rr] = mnv;
    }
    oH[t] = hn; oC[t] = cn; oN[t] = nn; oM[t] = mn;
  }

  // ---- store phase: LDS transpose -> fully-coalesced 1KB NT stores ----
  // Region holds one 64x128 f32 array (32 KB); 4 rounds (h,c,n,m).
  const int srow = wave * 16 + l15;                 // 0..63
  const int wswz = (l15 & 7) << 4;                  // srow&7 == l15&7
#define STORE_ROUND(REGS, AOFF)                                              \
  {                                                                          \
    _Pragma("unroll")                                                        \
    for (int t = 0; t < 8; ++t) {                                            \
      int addr = (srow * 512 + (jb + 16 * t) * 4) ^ wswz;                    \
      *reinterpret_cast<f32x4*>(smem + addr) = REGS[t];                      \
    }                                                                        \
    __syncthreads();                                                         \
    _Pragma("unroll")                                                        \
    for (int i = 0; i < 8; ++i) {                                            \
      int flat = (i * 256 + tid) * 4;                                        \
      int row  = flat >> 7;                                                  \
      f32x4 v  = *reinterpret_cast<const f32x4*>(                            \
          smem + ((flat * 4) ^ ((row & 7) << 4)));                           \
      __builtin_nontemporal_store(                                           \
          v, reinterpret_cast<f32x4*>(out + (AOFF) + (size_t)row0 * HD + flat)); \
    }                                                                        \
    __syncthreads();                                                         \
  }

  STORE_ROUND(oH, 0)
  STORE_ROUND(oC, OUTQ)
  STORE_ROUND(oN, 2 * OUTQ)
  STORE_ROUND(oM, 3 * OUTQ)
#undef STORE_ROUND
}

extern "C" void kernel_launch(void* const* d_in, const int* in_sizes, int n_in,
                              void* d_out, int out_size, void* d_ws, size_t ws_size,
                              hipStream_t stream) {
  const float* x = (const float*)d_in[0];
  const float* h = (const float*)d_in[1];
  const float* c = (const float*)d_in[2];
  const float* n = (const float*)d_in[3];
  const float* m = (const float*)d_in[4];
  const float* W = (const float*)d_in[5];
  const float* r = (const float*)d_in[6];
  const float* b = (const float*)d_in[7];
  uint16_t* Bp = (uint16_t*)d_ws;   // 256 KB packed bf16 weights

  pack_weights<<<64, 256, 0, stream>>>(W, r, Bp);
  slstm_fused<<<NROWS / 64, 256, 0, stream>>>(x, h, c, n, m, b, Bp, (float*)d_out);
}

// Round 8
// 181.500 us; speedup vs baseline: 1.5899x; 1.5899x over previous
//
#include <hip/hip_runtime.h>
#include <cstdint>

#define NROWS 131072
#define HD    128      // H == IN == 128
#define NDIM  512      // 4*H
#define OUTQ  16777216 // NROWS*HD

using bf16x8 = __attribute__((ext_vector_type(8))) short;
using f32x4  = __attribute__((ext_vector_type(4))) float;

__device__ __forceinline__ uint32_t bf16rne(float f) {
  uint32_t u = __builtin_bit_cast(uint32_t, f);
  return (u + 0x7fffu + ((u >> 16) & 1u)) >> 16;
}

__device__ __forceinline__ float tanhf_fast(float v) {
  float a = __builtin_fabsf(v);
  float e = __expf(-2.0f * a);
  float t = (1.0f - e) * __builtin_amdgcn_rcpf(1.0f + e);
  return v < 0.0f ? -t : t;
}

__device__ __forceinline__ f32x4 ldv(const float* p) {
  return *reinterpret_cast<const f32x4*>(p);
}

// Async global->LDS DMA, 16B per lane. LDS dest = uniform base + lane*16.
#define ASYNC16(g, l)                                                        \
  __builtin_amdgcn_global_load_lds(                                          \
      (const __attribute__((address_space(1))) void*)(g),                    \
      (__attribute__((address_space(3))) void*)(l), 16, 0, 0)

// Pack Wf[k][n] = W[k][n] + (k>=128 ? r[k-128][n] : 0) as bf16 fragments.
// Frag (g*8 + t)*8 + s (1 KB each): element j of lane l =
//   Wf[s*32 + (l>>4)*8 + j][gate g, col t*16 + (l&15)].
// Serves as the MFMA A-operand of Wf^T (rows = gate cols).
__global__ __launch_bounds__(256) void pack_weights(
    const float* __restrict__ W, const float* __restrict__ r,
    uint16_t* __restrict__ Bp) {
  int idx = blockIdx.x * 256 + threadIdx.x;   // 16384 frags total
  int l  = idx & 63;
  int ts = idx >> 6;
  int s  = ts & 7;
  int t  = ts >> 3;
  int ncol  = t * 16 + (l & 15);
  int kbase = s * 32 + ((l >> 4) << 3);
  uint32_t w[4];
#pragma unroll
  for (int jj = 0; jj < 4; ++jj) {
    int k0 = kbase + 2 * jj;
    float v0 = W[k0 * NDIM + ncol];
    float v1 = W[(k0 + 1) * NDIM + ncol];
    if (k0 >= 128)     v0 += r[(k0 - 128) * NDIM + ncol];
    if (k0 + 1 >= 128) v1 += r[(k0 + 1 - 128) * NDIM + ncol];
    w[jj] = bf16rne(v0) | (bf16rne(v1) << 16);
  }
  reinterpret_cast<uint4*>(Bp)[idx] = make_uint4(w[0], w[1], w[2], w[3]);
}

__global__ __launch_bounds__(256, 4) void slstm_fused(
    const float* __restrict__ x,  const float* __restrict__ h,
    const float* __restrict__ cs, const float* __restrict__ ns,
    const float* __restrict__ ms, const float* __restrict__ bias,
    const uint16_t* __restrict__ Bp, float* __restrict__ out) {
  // LDS = weight tile buffer only (32 frags x 1 KB).
  __shared__ __align__(16) char smem[32768];
  const int tid  = threadIdx.x;
  const int wave = tid >> 6;
  const int lane = tid & 63;
  const int row0 = blockIdx.x * 64;
  const int l15  = lane & 15;
  const int lg   = lane >> 4;

  // Transposed D layout: lane owns batchrow = wave*16 + l15 and gate-cols
  // 16*t + 4*lg + rr (rr=0..3) -> all epilogue I/O is f32x4.
  const int    myrow = row0 + wave * 16 + l15;
  const size_t rbase = (size_t)myrow * HD;
  const int    jb    = lg * 4;

  // c/n/m tile-0 prefetch (longest possible issue-to-use distance)
  f32x4 cvA = ldv(cs + rbase + jb);
  f32x4 nvA = ldv(ns + rbase + jb);
  f32x4 mvA = ldv(ms + rbase + jb);
  f32x4 cvB = {0,0,0,0}, nvB = {0,0,0,0}, mvB = {0,0,0,0};

  // DMA weight tile 0: wave w stages gate w, k-steps 0..7 (wave-private 8KB)
  const char* wBytes = (const char*)Bp;
  {
    const char* gsrc = wBytes + (((size_t)(wave * 8 + 0) * 8) << 10) + (lane << 4);
    char* ldst = smem + (wave << 13);
#pragma unroll
    for (int k = 0; k < 8; ++k)
      ASYNC16(gsrc + (k << 10), ldst + (k << 10));
  }

  // ---- A/B fragments loaded DIRECTLY from global (no LDS staging):
  // lane needs xh[myrow][s*32 + lg*8 + j], j=0..7 -> contiguous 32B.
  bf16x8 a[8];
#pragma unroll
  for (int s = 0; s < 8; ++s) {
    const float* src = (s < 4 ? x : h) + rbase + ((s & 3) * 32 + lg * 8);
    f32x4 v0 = ldv(src);
    f32x4 v1 = ldv(src + 4);
    bf16x8 pk;
    pk[0] = (short)bf16rne(v0[0]);
    pk[1] = (short)bf16rne(v0[1]);
    pk[2] = (short)bf16rne(v0[2]);
    pk[3] = (short)bf16rne(v0[3]);
    pk[4] = (short)bf16rne(v1[0]);
    pk[5] = (short)bf16rne(v1[1]);
    pk[6] = (short)bf16rne(v1[2]);
    pk[7] = (short)bf16rne(v1[3]);
    a[s] = pk;
  }

  // ---- 8 column tiles, fully unrolled; R4's proven 2-barrier scheme ----
#pragma unroll
  for (int t = 0; t < 8; ++t) {
    __syncthreads();   // barrier A: vm drain -> tile t weights visible

    if (t < 7) {       // prefetch c/n/m for t+1
      const size_t pp = rbase + jb + 16 * (t + 1);
      cvB = ldv(cs + pp);
      nvB = ldv(ns + pp);
      mvB = ldv(ms + pp);
    }
    const int j0 = jb + 16 * t;
    const f32x4 bI = ldv(bias + j0);
    const f32x4 bF = ldv(bias + 128 + j0);
    const f32x4 bZ = ldv(bias + 256 + j0);
    const f32x4 bO = ldv(bias + 384 + j0);

    f32x4 accI = {0.f, 0.f, 0.f, 0.f};
    f32x4 accF = {0.f, 0.f, 0.f, 0.f};
    f32x4 accZ = {0.f, 0.f, 0.f, 0.f};
    f32x4 accO = {0.f, 0.f, 0.f, 0.f};
#pragma unroll
    for (int s = 0; s < 8; ++s) {
      const int lo = lane << 4;
      bf16x8 wI = *reinterpret_cast<const bf16x8*>(smem + ((0 * 8 + s) << 10) + lo);
      bf16x8 wF = *reinterpret_cast<const bf16x8*>(smem + ((1 * 8 + s) << 10) + lo);
      bf16x8 wZ = *reinterpret_cast<const bf16x8*>(smem + ((2 * 8 + s) << 10) + lo);
      bf16x8 wO = *reinterpret_cast<const bf16x8*>(smem + ((3 * 8 + s) << 10) + lo);
      accI = __builtin_amdgcn_mfma_f32_16x16x32_bf16(wI, a[s], accI, 0, 0, 0);
      accF = __builtin_amdgcn_mfma_f32_16x16x32_bf16(wF, a[s], accF, 0, 0, 0);
      accZ = __builtin_amdgcn_mfma_f32_16x16x32_bf16(wZ, a[s], accZ, 0, 0, 0);
      accO = __builtin_amdgcn_mfma_f32_16x16x32_bf16(wO, a[s], accO, 0, 0, 0);
    }
    __syncthreads();   // barrier B: all waves done reading tile t weights

    if (t < 7) {       // DMA tile t+1; latency hides under epilogue
      const char* gsrc = wBytes + (((size_t)(wave * 8 + (t + 1)) * 8) << 10) + (lane << 4);
      char* ldst = smem + (wave << 13);
#pragma unroll
      for (int k = 0; k < 8; ++k)
        ASYNC16(gsrc + (k << 10), ldst + (k << 10));
    }

    f32x4 hn, cn, nn, mn;
#pragma unroll
    for (int rr = 0; rr < 4; ++rr) {
      float i_raw = accI[rr] + bI[rr];
      float f_raw = accF[rr] + bF[rr];
      float z_raw = accZ[rr] + bZ[rr];
      float o_raw = accO[rr] + bO[rr];
      float ef  = __expf(-f_raw);
      float den = 1.0f + ef;
      float fg  = __builtin_amdgcn_rcpf(den);   // sigmoid(f_raw)
      float lgf = -__logf(den);                 // log sigmoid(f_raw)
      float mnv = fmaxf(lgf + mvA[rr], i_raw);  // m_new
      float ip  = __expf(i_raw - mnv);          // i'
      float zt  = tanhf_fast(z_raw);
      float og  = __builtin_amdgcn_rcpf(1.0f + __expf(-o_raw));
      float cnv = fg * cvA[rr] + ip * zt;       // c_new (f' == f per source)
      float nnv = fg * nvA[rr] + ip;            // n_new
      hn[rr] = og * tanhf_fast(cnv * __builtin_amdgcn_rcpf(nnv));
      cn[rr] = cnv;
      nn[rr] = nnv;
      mn[rr] = mnv;
    }
    const size_t p = rbase + jb + 16 * t;
    *reinterpret_cast<f32x4*>(out + p)            = hn;
    *reinterpret_cast<f32x4*>(out + OUTQ + p)     = cn;
    *reinterpret_cast<f32x4*>(out + 2 * OUTQ + p) = nn;
    *reinterpret_cast<f32x4*>(out + 3 * OUTQ + p) = mn;

    cvA = cvB; nvA = nvB; mvA = mvB;
  }
}

extern "C" void kernel_launch(void* const* d_in, const int* in_sizes, int n_in,
                              void* d_out, int out_size, void* d_ws, size_t ws_size,
                              hipStream_t stream) {
  const float* x = (const float*)d_in[0];
  const float* h = (const float*)d_in[1];
  const float* c = (const float*)d_in[2];
  const float* n = (const float*)d_in[3];
  const float* m = (const float*)d_in[4];
  const float* W = (const float*)d_in[5];
  const float* r = (const float*)d_in[6];
  const float* b = (const float*)d_in[7];
  uint16_t* Bp = (uint16_t*)d_ws;   // 256 KB packed bf16 weights

  pack_weights<<<64, 256, 0, stream>>>(W, r, Bp);
  slstm_fused<<<NROWS / 64, 256, 0, stream>>>(x, h, c, n, m, b, Bp, (float*)d_out);
}